// Round 18
// baseline (276.372 us; speedup 1.0000x reference)
//
#include <hip/hip_runtime.h>
#include <hip/hip_bf16.h>

#define TPB 256
static constexpr int BATCH = 4;
static constexpr int NPTS  = 4096;
static constexpr int BN    = BATCH * NPTS;   // 16384 columns for all GEMMs

typedef __attribute__((ext_vector_type(8))) short short8v;
typedef __attribute__((ext_vector_type(4))) short short4v;
typedef __attribute__((ext_vector_type(4))) float f32x4;

struct Seg { const float* in; const float* W; int C; int ws; };

__device__ __forceinline__ void gload16(const void* g, void* l) {
    __builtin_amdgcn_global_load_lds(
        (const __attribute__((address_space(1))) void*)g,
        (__attribute__((address_space(3))) void*)l, 16, 0, 0);
}

// ---------------------------------------------------------------------------
// MFMA GEMM (verified): D[m][col] = bias[m] + sum_k A[m][k]*B[k][col]
// ---------------------------------------------------------------------------
template<int EPI>
__global__ __launch_bounds__(256)
void gemm_k(const __hip_bfloat16* __restrict__ A, const __hip_bfloat16* __restrict__ B,
            const float* __restrict__ bias, float* __restrict__ outF,
            __hip_bfloat16* __restrict__ outB, int Kp, int rowOff)
{
    __shared__ short Alds[8192];
    __shared__ short Blds[8704];
    const int tid = threadIdx.x, lane = tid & 63, wid = tid >> 6;
    const int wm = wid & 1, wn = wid >> 1;
    const int n0 = blockIdx.x * 128, m0 = blockIdx.y * 128;

    const char* asrc[4]; short* adst[4];
    #pragma unroll
    for (int t = 0; t < 4; ++t) {
        const int g = (wid * 4 + t) * 64 + lane;
        const int arow = g >> 3, ai = g & 7;
        asrc[t] = (const char*)A +
                  (((size_t)(m0 + arow)) * Kp + ((ai ^ (arow & 7)) << 3)) * 2;
        adst[t] = &Alds[(wid * 4 + t) * 512];
    }
    const char* bsrc[2]; int bkp[2], bc0[2];
    #pragma unroll
    for (int it = 0; it < 2; ++it) {
        const int q = it * 256 + tid;
        bkp[it] = q >> 4;
        bc0[it] = (q & 15) * 8;
        bsrc[it] = (const char*)B +
                   (((size_t)(bkp[it] * 2)) * BN + (n0 + bc0[it])) * 2;
    }

    f32x4 acc[4][4];
    #pragma unroll
    for (int i = 0; i < 4; ++i)
        #pragma unroll
        for (int j = 0; j < 4; ++j) acc[i][j] = (f32x4){0.f, 0.f, 0.f, 0.f};

    const int rl = lane & 15, g4 = lane >> 4;

    const int nkt = Kp >> 6;
    for (int kt = 0; kt < nkt; ++kt) {
        __syncthreads();
        short8v blo[2], bhi[2];
        #pragma unroll
        for (int it = 0; it < 2; ++it) {
            blo[it] = *(const short8v*)(bsrc[it]);
            bhi[it] = *(const short8v*)(bsrc[it] + (size_t)BN * 2);
            bsrc[it] += (size_t)64 * BN * 2;
        }
        #pragma unroll
        for (int t = 0; t < 4; ++t) {
            gload16(asrc[t], adst[t]);
            asrc[t] += 128;
        }
        #pragma unroll
        for (int it = 0; it < 2; ++it) {
            #pragma unroll
            for (int j = 0; j < 8; ++j) {
                const int c = bc0[it] + j;
                const int val = ((int)(unsigned short)blo[it][j]) |
                                (((int)(unsigned short)bhi[it][j]) << 16);
                *(int*)((char*)Blds + c * 136 + bkp[it] * 4) = val;
            }
        }
        __syncthreads();

        #pragma unroll
        for (int ks = 0; ks < 2; ++ks) {
            short8v af[4];
            #pragma unroll
            for (int mf = 0; mf < 4; ++mf) {
                const int row = wm * 64 + mf * 16 + rl;
                const int base = row * 128, sw = (row & 7) << 4;
                const short4v lo = *(const short4v*)((const char*)Alds +
                                    (base + ((ks * 64 + (g4 << 3)) ^ sw)));
                const short4v hi = *(const short4v*)((const char*)Alds +
                                    (base + ((ks * 64 + (g4 << 3) + 32) ^ sw)));
                af[mf] = __builtin_shufflevector(lo, hi, 0,1,2,3,4,5,6,7);
            }
            short8v bfv[4];
            #pragma unroll
            for (int nf = 0; nf < 4; ++nf) {
                const int colr = wn * 64 + nf * 16 + rl;
                const char* bp = (const char*)Blds + colr * 136 + ks * 64 + (g4 << 3);
                const short4v lo = *(const short4v*)bp;
                const short4v hi = *(const short4v*)(bp + 32);
                bfv[nf] = __builtin_shufflevector(lo, hi, 0,1,2,3,4,5,6,7);
            }
            #pragma unroll
            for (int mf = 0; mf < 4; ++mf)
                #pragma unroll
                for (int nf = 0; nf < 4; ++nf)
                    acc[mf][nf] = __builtin_amdgcn_mfma_f32_16x16x32_bf16(
                        af[mf], bfv[nf], acc[mf][nf], 0, 0, 0);
        }
    }

    #pragma unroll
    for (int mf = 0; mf < 4; ++mf) {
        #pragma unroll
        for (int i = 0; i < 4; ++i) {
            const int row = m0 + wm * 64 + mf * 16 + g4 * 4 + i;
            const float bs = bias[row];
            #pragma unroll
            for (int nf = 0; nf < 4; ++nf) {
                const int col = n0 + wn * 64 + nf * 16 + rl;
                float v = acc[mf][nf][i] + bs;
                if (EPI == 1) {
                    v = fmaxf(v, 0.f);
                    outB[(size_t)(rowOff + row) * BN + col] = __float2bfloat16(v);
                } else {
                    outF[(size_t)row * BN + col] = v;
                }
            }
        }
    }
}

// ---------------------------------------------------------------------------
// small f32 conv — h1/h2 only (grid path must stay f32; R13/R17 lesson: bf16
// anywhere in the grid path amplifies x H/2 through bilinear sampling).
// ---------------------------------------------------------------------------
template<bool RELU, int OT>
__global__ __launch_bounds__(TPB)
void conv1x1_k(Seg s0, Seg s1, int nseg, int Ctot,
               const float* __restrict__ bias, float* __restrict__ out, int O)
{
    __shared__ float Wl[131][OT];
    const int n  = blockIdx.x * TPB + threadIdx.x;
    const int o0 = blockIdx.y * OT;
    const int b  = blockIdx.z;
    Seg segs[2] = {s0, s1};
    int off[3]; off[0] = 0;
    #pragma unroll
    for (int k = 0; k < 2; ++k) off[k + 1] = off[k] + (k < nseg ? segs[k].C : 0);
    for (int idx = threadIdx.x; idx < Ctot * OT; idx += TPB) {
        int c = idx / OT, t = idx % OT;
        int k = (nseg > 1 && c >= off[1]) ? 1 : 0;
        Wl[c][t] = segs[k].W[(size_t)(o0 + t) * segs[k].ws + (c - off[k])];
    }
    __syncthreads();
    float acc[OT];
    #pragma unroll
    for (int t = 0; t < OT; ++t) acc[t] = 0.f;
    int cbase = 0;
    for (int k = 0; k < nseg; ++k) {
        const float* ip = segs[k].in + (size_t)b * segs[k].C * NPTS + n;
        const int C = segs[k].C;
        #pragma unroll 4
        for (int cc = 0; cc < C; ++cc) {
            float v = ip[(size_t)cc * NPTS];
            const float4* wr = (const float4*)(&Wl[cbase + cc][0]);
            #pragma unroll
            for (int q = 0; q < OT / 4; ++q) {
                float4 w = wr[q];
                acc[4*q+0] += w.x * v; acc[4*q+1] += w.y * v;
                acc[4*q+2] += w.z * v; acc[4*q+3] += w.w * v;
            }
        }
        cbase += C;
    }
    #pragma unroll
    for (int t = 0; t < OT; ++t) {
        float r = acc[t] + bias[o0 + t];
        if (RELU) r = fmaxf(r, 0.f);
        out[((size_t)b * O + o0 + t) * NPTS + n] = r;
    }
}

// ---------------------------------------------------------------------------
// Fused weight prep: ONE kernel for wcomp + biasfill + all 7 Wb assemblies.
// ---------------------------------------------------------------------------
__global__ __launch_bounds__(TPB)
void prepall_k(const float* __restrict__ Wr1, const float* __restrict__ Wn1,
               const float* __restrict__ Wl1, const float* __restrict__ Wl2,
               const float* __restrict__ bl2, const float* __restrict__ b1,
               const float* __restrict__ Wr2, const float* __restrict__ Wn2,
               const float* __restrict__ Wr3, const float* __restrict__ Wn3,
               const float* __restrict__ b2, const float* __restrict__ b3,
               __hip_bfloat16* __restrict__ Wb1, __hip_bfloat16* __restrict__ Wb2,
               __hip_bfloat16* __restrict__ Wb3, __hip_bfloat16* __restrict__ Wb4,
               float* __restrict__ bu1, float* __restrict__ bv1,
               float* __restrict__ bias3, float* __restrict__ bias4)
{
    __shared__ float wrow[256];
    const int id = blockIdx.x, k = threadIdx.x;

    if (id < 512) {                      // Wb2 + composed Wc + biases
        const int isv = id >> 8, r = id & 255;
        const float* W = isv ? Wn1 : Wr1;
        wrow[k] = W[(size_t)r * 387 + 131 + k];
        __syncthreads();
        float acc = 0.f;
        for (int o = 0; o < 256; ++o) acc += wrow[o] * Wl2[(size_t)o * 256 + k];
        const size_t row = (size_t)(isv * 256 + r);
        Wb2[row * 448 + 131 + k] = __float2bfloat16(acc);
        if (k < 131) Wb2[row * 448 + k] = __float2bfloat16(W[(size_t)r * 387 + k]);
        if (k == 0) {
            float s = 0.f;
            for (int o = 0; o < 256; ++o) s += wrow[o] * bl2[o];
            if (isv) bv1[r] = s; else bu1[r] = b1[r] + s;
        }
    } else if (id < 768) {               // Wb1 (256 rows x 448)
        const int r = id - 512;
        #pragma unroll
        for (int t = 0; t < 2; ++t) {
            const int c = t * 256 + k;
            if (c < 448)
                Wb1[(size_t)r * 448 + c] = __float2bfloat16(Wl1[(size_t)r * 448 + c]);
        }
    } else if (id < 1280) {              // Wb3 (512 rows x 320, src 259 cols)
        const int tb = id - 768, isv = tb >> 8, r = tb & 255;
        const float* W = isv ? Wn2 : Wr2;
        const size_t row = (size_t)(isv * 256 + r);
        #pragma unroll
        for (int t = 0; t < 2; ++t) {
            const int c = t * 256 + k;
            if (c < 320) {
                float v = (c < 259) ? W[(size_t)r * 259 + c] : 0.f;
                Wb3[row * 320 + c] = __float2bfloat16(v);
            }
        }
    } else if (id < 1536) {              // Wb4 (256 rows x 320, src 259 cols)
        const int tb = id - 1280, isv = tb >> 7, r = tb & 127;
        const float* W = isv ? Wn3 : Wr3;
        const size_t row = (size_t)(isv * 128 + r);
        #pragma unroll
        for (int t = 0; t < 2; ++t) {
            const int c = t * 256 + k;
            if (c < 320) {
                float v = (c < 259) ? W[(size_t)r * 259 + c] : 0.f;
                Wb4[row * 320 + c] = __float2bfloat16(v);
            }
        }
    } else {                             // bias fills
        #pragma unroll
        for (int t = 0; t < 3; ++t) {
            const int i = t * 256 + k;
            if (i < 512) bias3[i] = (i < 256) ? b2[i] : 0.f;
            else if (i < 768) { int j = i - 512; bias4[j] = (j < 128) ? b3[j] : 0.f; }
        }
    }
}

// ---------------------------------------------------------------------------
// KNN (K=3). Chunked float4(x,y,z,sq) staging, conflict-free; 16q x 16s.
// Strict < serial scan (exact); butterfly merge keeps full lex compare.
// ---------------------------------------------------------------------------
__global__ __launch_bounds__(TPB)
void knn_k(const float* __restrict__ loc, int* __restrict__ idxp)
{
    __shared__ float4 pt[1024];
    const int b = blockIdx.y;
    const float* L = loc + (size_t)b * 3 * NPTS;

    const int ql = threadIdx.x >> 4;
    const int s  = threadIdx.x & 15;
    const int i  = blockIdx.x * 16 + ql;

    const float xi = L[i], yi = L[NPTS + i], zi = L[2 * NPTS + i];
    float sqi;
    {
        #pragma clang fp contract(off)
        sqi = xi * xi + yi * yi + zi * zi;
    }

    float d0 = 3e38f, d1 = 3e38f, d2 = 3e38f;
    int   i0 = 0x7fffffff, i1 = 0x7fffffff, i2 = 0x7fffffff;

    for (int c = 0; c < NPTS / 1024; ++c) {
        __syncthreads();
        {
            const int base = c * 1024;
            #pragma unroll
            for (int t = 0; t < 4; ++t) {
                const int p = t * 256 + threadIdx.x;
                const float x = L[base + p];
                const float y = L[NPTS + base + p];
                const float z = L[2 * NPTS + base + p];
                float sq;
                {
                    #pragma clang fp contract(off)
                    sq = x * x + y * y + z * z;
                }
                pt[p] = make_float4(x, y, z, sq);
            }
        }
        __syncthreads();

        #pragma unroll 4
        for (int k = 0; k < 1024 / 16; ++k) {
            const int jj = (k << 4) | s;
            const float4 p = pt[jj];
            const int j = (c << 10) | jj;
            float d;
            {
                #pragma clang fp contract(off)
                float dot = xi * p.x + yi * p.y + zi * p.z;
                d = (sqi + p.w) - 2.0f * dot;
            }
            d = (j == i) ? 3e38f : d;
            const bool lt2 = d < d2, lt1 = d < d1, lt0 = d < d0;
            d2 = lt1 ? d1 : (lt2 ? d : d2);  i2 = lt1 ? i1 : (lt2 ? j : i2);
            d1 = lt0 ? d0 : (lt1 ? d : d1);  i1 = lt0 ? i0 : (lt1 ? j : i1);
            d0 = lt0 ? d  : d0;              i0 = lt0 ? j  : i0;
        }
    }

    #pragma unroll
    for (int m = 1; m <= 8; m <<= 1) {
        float e0 = __shfl_xor(d0, m), e1 = __shfl_xor(d1, m), e2 = __shfl_xor(d2, m);
        int   j0 = __shfl_xor(i0, m), j1 = __shfl_xor(i1, m), j2 = __shfl_xor(i2, m);
        float ee[3] = {e0, e1, e2};
        int   jj[3] = {j0, j1, j2};
        #pragma unroll
        for (int t = 0; t < 3; ++t) {
            const float e = ee[t]; const int je = jj[t];
            const bool lt2 = (e < d2 || (e == d2 && je < i2));
            const bool lt1 = (e < d1 || (e == d1 && je < i1));
            const bool lt0 = (e < d0 || (e == d0 && je < i0));
            d2 = lt1 ? d1 : (lt2 ? e : d2);  i2 = lt1 ? i1 : (lt2 ? je : i2);
            d1 = lt0 ? d0 : (lt1 ? e : d1);  i1 = lt0 ? i0 : (lt1 ? je : i1);
            d0 = lt0 ? e  : d0;              i0 = lt0 ? je : i0;
        }
    }

    if (s == 0) {
        idxp[0 * BN + b * NPTS + i] = i0;
        idxp[1 * BN + b * NPTS + i] = i1;
        idxp[2 * BN + b * NPTS + i] = i2;
    }
}

// ---------------------------------------------------------------------------
__global__ __launch_bounds__(TPB)
void gridconv_k(const float* __restrict__ loc, const float* __restrict__ h2,
                const float* __restrict__ Wg, const float* __restrict__ bg,
                float* __restrict__ gridv)
{
    const int n = blockIdx.x * TPB + threadIdx.x;
    const int b = blockIdx.y;
    float a0 = bg[0], a1 = bg[1];
    #pragma unroll
    for (int c = 0; c < 3; ++c) {
        float v = loc[((size_t)b * 3 + c) * NPTS + n];
        a0 += Wg[c] * v; a1 += Wg[67 + c] * v;
    }
    const float* hp = h2 + (size_t)b * 64 * NPTS + n;
    #pragma unroll 4
    for (int c = 0; c < 64; ++c) {
        float v = hp[(size_t)c * NPTS];
        a0 += Wg[3 + c] * v; a1 += Wg[70 + c] * v;
    }
    gridv[((size_t)b * 2 + 0) * NPTS + n] = a0;
    gridv[((size_t)b * 2 + 1) * NPTS + n] = a1;
}

// ---------------------------------------------------------------------------
// grid_sample, 4 channels per thread (verified R16).
// ---------------------------------------------------------------------------
__global__ __launch_bounds__(TPB)
void gridsample4_k(const float* __restrict__ gridv, const float* __restrict__ p0,
                   const float* __restrict__ p1, const float* __restrict__ p2,
                   __hip_bfloat16* __restrict__ pooledbf)
{
    const int n     = blockIdx.x * 64 + (threadIdx.x & 63);
    const int cidx0 = blockIdx.y * 16 + (threadIdx.x >> 6) * 4;
    const int b     = blockIdx.z;
    const float* img; int C, H, cbase;
    if (cidx0 < 64)       { img = p0; C = 64;  H = 112; cbase = 0; }
    else if (cidx0 < 192) { img = p1; C = 128; H = 56;  cbase = 64; }
    else                  { img = p2; C = 256; H = 28;  cbase = 192; }
    const float gx = gridv[((size_t)b * 2 + 0) * NPTS + n];
    const float gy = gridv[((size_t)b * 2 + 1) * NPTS + n];
    float wx, wy; int x0, x1, y0, y1;
    {
        #pragma clang fp contract(off)
        float ix  = ((gx + 1.0f) * (float)H - 1.0f) * 0.5f;
        float iy  = ((gy + 1.0f) * (float)H - 1.0f) * 0.5f;
        float ix0 = floorf(ix), iy0 = floorf(iy);
        wx = ix - ix0; wy = iy - iy0;
        x0 = min(max((int)ix0, 0),     H - 1);
        x1 = min(max((int)ix0 + 1, 0), H - 1);
        y0 = min(max((int)iy0, 0),     H - 1);
        y1 = min(max((int)iy0 + 1, 0), H - 1);
    }
    const float w00 = (1.f - wx) * (1.f - wy), w01 = wx * (1.f - wy);
    const float w10 = (1.f - wx) * wy,         w11 = wx * wy;
    const int plane = H * H;
    const float* base = img + ((size_t)b * C + (cidx0 - cbase)) * plane;
    #pragma unroll
    for (int cc = 0; cc < 4; ++cc) {
        const float* pl = base + (size_t)cc * plane;
        float v = pl[y0*H + x0] * w00 + pl[y0*H + x1] * w01
                + pl[y1*H + x0] * w10 + pl[y1*H + x1] * w11;
        pooledbf[(size_t)(cidx0 + cc) * BN + b * NPTS + n] = __float2bfloat16(v);
    }
}

// ---------------------------------------------------------------------------
// Xc1 prep: rows 0..2 loc-cast, 3..130 feat-cast, 387..447 zero.
// ---------------------------------------------------------------------------
__global__ __launch_bounds__(TPB)
void xc1prep_k(const float* __restrict__ x_loc, const float* __restrict__ x_feat,
               __hip_bfloat16* __restrict__ Xc1)
{
    const int n = blockIdx.x * TPB + threadIdx.x;
    const int y = blockIdx.y, b = blockIdx.z;
    if (y < 3) {
        Xc1[(size_t)y * BN + b * NPTS + n] =
            __float2bfloat16(x_loc[((size_t)b * 3 + y) * NPTS + n]);
    } else if (y < 131) {
        const int c = y - 3;
        Xc1[(size_t)y * BN + b * NPTS + n] =
            __float2bfloat16(x_feat[((size_t)b * 128 + c) * NPTS + n]);
    } else {
        const int row = 387 + (y - 131);
        Xc1[(size_t)row * BN + b * NPTS + n] = __float2bfloat16(0.f);
    }
}

// ---------------------------------------------------------------------------
// Gather + next-layer input prep (verified R16). Grid (320, BATCH).
// ---------------------------------------------------------------------------
__global__ __launch_bounds__(TPB)
void gatherprep_k(const float* __restrict__ uv, const int* __restrict__ idxp,
                  const float* __restrict__ x_loc, __hip_bfloat16* __restrict__ Xc)
{
    __shared__ float vl[NPTS];   // 16 KB
    const int cx = blockIdx.x, b = blockIdx.y;

    if (cx < 3) {
        #pragma unroll
        for (int t = 0; t < NPTS / TPB; ++t) {
            const int n = t * TPB + threadIdx.x;
            Xc[(size_t)cx * BN + b * NPTS + n] =
                __float2bfloat16(x_loc[((size_t)b * 3 + cx) * NPTS + n]);
        }
        return;
    }
    if (cx >= 259) {
        #pragma unroll
        for (int t = 0; t < NPTS / TPB; ++t) {
            const int n = t * TPB + threadIdx.x;
            Xc[(size_t)cx * BN + b * NPTS + n] = __float2bfloat16(0.f);
        }
        return;
    }
    const int c = cx - 3;
    const float* u = uv + (size_t)c * BN + b * NPTS;
    const float* v = uv + (size_t)(256 + c) * BN + b * NPTS;
    #pragma unroll
    for (int t = 0; t < NPTS / TPB; ++t)
        vl[t * TPB + threadIdx.x] = v[t * TPB + threadIdx.x];
    __syncthreads();
    #pragma unroll
    for (int t = 0; t < NPTS / TPB; ++t) {
        const int n = t * TPB + threadIdx.x;
        const int j0 = idxp[0 * BN + b * NPTS + n] & (NPTS - 1);
        const int j1 = idxp[1 * BN + b * NPTS + n] & (NPTS - 1);
        const int j2 = idxp[2 * BN + b * NPTS + n] & (NPTS - 1);
        float r = u[n] + vl[j0] + vl[j1] + vl[j2];
        Xc[(size_t)cx * BN + b * NPTS + n] = __float2bfloat16(fmaxf(r, 0.f));
    }
}

// ---------------------------------------------------------------------------
// layer-3 gather + Wloc head, channel-parallel (verified R14-R16).
// ---------------------------------------------------------------------------
__global__ __launch_bounds__(TPB)
void finalfuse_k(const float* __restrict__ uv, const int* __restrict__ idxp,
                 const float* __restrict__ loc,
                 const float* __restrict__ Wloc, const float* __restrict__ bloc,
                 float* __restrict__ outloc, float* __restrict__ outfeat)
{
    __shared__ float wl[393];
    __shared__ float part[16][16][3];
    for (int idx = threadIdx.x; idx < 393; idx += TPB) wl[idx] = Wloc[idx];
    __syncthreads();

    const int nl = threadIdx.x & 15, cg = threadIdx.x >> 4;
    const int n = blockIdx.x * 16 + nl;
    const int b = blockIdx.y;
    const int j0 = idxp[0 * BN + b * NPTS + n] & (NPTS - 1);
    const int j1 = idxp[1 * BN + b * NPTS + n] & (NPTS - 1);
    const int j2 = idxp[2 * BN + b * NPTS + n] & (NPTS - 1);

    float a0 = 0.f, a1 = 0.f, a2 = 0.f;
    #pragma unroll
    for (int cc = 0; cc < 8; ++cc) {
        const int c = cg * 8 + cc;
        const float* u = uv + (size_t)c * BN + b * NPTS;
        const float* v = uv + (size_t)(128 + c) * BN + b * NPTS;
        float f = fmaxf(u[n] + v[j0] + v[j1] + v[j2], 0.f);
        outfeat[((size_t)b * 128 + c) * NPTS + n] = f;
        a0 += wl[3 + c] * f; a1 += wl[134 + c] * f; a2 += wl[265 + c] * f;
    }
    part[cg][nl][0] = a0; part[cg][nl][1] = a1; part[cg][nl][2] = a2;
    __syncthreads();

    if (cg == 0) {
        float b0 = bloc[0], b1v = bloc[1], b2v = bloc[2];
        float l[3];
        #pragma unroll
        for (int c = 0; c < 3; ++c) {
            float v = loc[((size_t)b * 3 + c) * NPTS + n];
            l[c] = v;
            b0 += wl[c] * v; b1v += wl[131 + c] * v; b2v += wl[262 + c] * v;
        }
        #pragma unroll
        for (int g = 0; g < 16; ++g) {
            b0 += part[g][nl][0]; b1v += part[g][nl][1]; b2v += part[g][nl][2];
        }
        outloc[((size_t)b * 3 + 0) * NPTS + n] = l[0] + tanhf(b0);
        outloc[((size_t)b * 3 + 1) * NPTS + n] = l[1] + tanhf(b1v);
        outloc[((size_t)b * 3 + 2) * NPTS + n] = l[2] + tanhf(b2v);
    }
}

__global__ __launch_bounds__(TPB)
void sentinel_k(float* __restrict__ out, int ntot, float c)
{
    int i = blockIdx.x * TPB + threadIdx.x;
    if (i < ntot) out[i] = c;
}

// ---------------------------------------------------------------------------
extern "C" void kernel_launch(void* const* d_in, const int* in_sizes, int n_in,
                              void* d_out, int out_size, void* d_ws, size_t ws_size,
                              hipStream_t stream)
{
    static const int EXP_INS[26] = {
        49152, 2097152, 3211264, 1605632, 802816,
        8384, 64, 4096, 64, 134, 2,
        114688, 256, 65536, 256,
        99072, 99072, 256, 66304, 66304, 256,
        33152, 33152, 128, 393, 3 };
    constexpr size_t WS_REQ = 16237824ull * 4ull;

    float code = -1.f;
    if (n_in != 26) code = 64.f;
    else {
        bool ok = true;
        for (int i = 0; i < 26; ++i) ok = ok && (in_sizes[i] == EXP_INS[i]);
        if (!ok) code = 24.f;
    }
    if (code < 0.f && out_size != 2146304) code = 32.f;
    if (code < 0.f && ws_size < WS_REQ)    code = 16.f;
    if (code >= 0.f) {
        sentinel_k<<<dim3((out_size + TPB - 1) / TPB), dim3(TPB), 0, stream>>>(
            (float*)d_out, out_size, code);
        return;
    }

    const float* x_loc  = (const float*)d_in[0];
    const float* x_feat = (const float*)d_in[1];
    const float* p0     = (const float*)d_in[2];
    const float* p1     = (const float*)d_in[3];
    const float* p2     = (const float*)d_in[4];
    const float* Ws1 = (const float*)d_in[5];  const float* bs1 = (const float*)d_in[6];
    const float* Ws2 = (const float*)d_in[7];  const float* bs2 = (const float*)d_in[8];
    const float* Wg  = (const float*)d_in[9];  const float* bg  = (const float*)d_in[10];
    const float* Wl1 = (const float*)d_in[11]; const float* bl1 = (const float*)d_in[12];
    const float* Wl2 = (const float*)d_in[13]; const float* bl2 = (const float*)d_in[14];
    const float* Wr1 = (const float*)d_in[15]; const float* Wn1 = (const float*)d_in[16];
    const float* b1  = (const float*)d_in[17];
    const float* Wr2 = (const float*)d_in[18]; const float* Wn2 = (const float*)d_in[19];
    const float* b2  = (const float*)d_in[20];
    const float* Wr3 = (const float*)d_in[21]; const float* Wn3 = (const float*)d_in[22];
    const float* b3  = (const float*)d_in[23];
    const float* Wloc= (const float*)d_in[24]; const float* bloc= (const float*)d_in[25];

    float* ws = (float*)d_ws;
    float* U  = ws;                       // 8,388,608 f: h1/h2 early, uv later
    float* h1 = U;
    float* h2 = U + 1048576;
    __hip_bfloat16* pooledbf = (__hip_bfloat16*)(ws + 8388608);
    __hip_bfloat16* Xc2      = pooledbf;
    __hip_bfloat16* Xc1 = (__hip_bfloat16*)(ws + 12058624);
    __hip_bfloat16* Xc3 = Xc1;
    float* S     = ws + 15728640;
    float* gridv = S;
    int*   idxp  = (int*)(S + 32768);
    float* bu1   = S + 212992;
    float* bv1   = S + 213248;
    float* bias3 = S + 213504;
    float* bias4 = S + 214016;
    __hip_bfloat16* Wb1 = (__hip_bfloat16*)(S + 214272);
    __hip_bfloat16* Wb2 = (__hip_bfloat16*)(S + 271616);
    __hip_bfloat16* Wb3 = (__hip_bfloat16*)(S + 386304);
    __hip_bfloat16* Wb4 = (__hip_bfloat16*)(S + 468224);

    float* out_loc  = (float*)d_out;
    float* out_feat = out_loc + (size_t)BATCH * 3 * NPTS;

    dim3 blk(TPB);
    const int GX = NPTS / TPB;   // 16
    Seg z{nullptr, nullptr, 0, 0};

    // 1) all weight prep in one kernel
    prepall_k<<<dim3(1537), blk, 0, stream>>>(
        Wr1, Wn1, Wl1, Wl2, bl2, b1, Wr2, Wn2, Wr3, Wn3, b2, b3,
        Wb1, Wb2, Wb3, Wb4, bu1, bv1, bias3, bias4);

    // 2-5) front-end (f32 — precision-critical grid path) + knn
    conv1x1_k<true, 8><<<dim3(GX, 8, BATCH), blk, 0, stream>>>(
        Seg{x_loc, Ws1, 3, 131}, Seg{x_feat, Ws1 + 3, 128, 131}, 2, 131, bs1, h1, 64);
    conv1x1_k<true, 8><<<dim3(GX, 8, BATCH), blk, 0, stream>>>(
        Seg{h1, Ws2, 64, 64}, z, 1, 64, bs2, h2, 64);
    gridconv_k<<<dim3(GX, BATCH), blk, 0, stream>>>(x_loc, h2, Wg, bg, gridv);
    knn_k<<<dim3(NPTS / 16, BATCH), blk, 0, stream>>>(x_loc, idxp);

    // 6) pooled (bf16, 4 channels/thread)
    gridsample4_k<<<dim3(NPTS / 64, 28, BATCH), blk, 0, stream>>>(
        gridv, p0, p1, p2, pooledbf);

    // 7) Xc1 rows 0..130 + zero rows 387..447
    xc1prep_k<<<dim3(GX, 192, BATCH), blk, 0, stream>>>(x_loc, x_feat, Xc1);
    // 8) G1: t = relu(Wl1@pooled + bl1) -> Xc1 rows 131..386
    gemm_k<1><<<dim3(128, 2), blk, 0, stream>>>(Wb1, pooledbf, bl1, nullptr, Xc1, 448, 131);

    // 9) G2: [u1; v1] = Wb2 @ Xc1 + [bu1; bv1]  (overwrites h1/h2 — consumed)
    gemm_k<0><<<dim3(128, 4), blk, 0, stream>>>(Wb2, Xc1, bu1, U, nullptr, 448, 0);
    // 10) Xc2 = [loc; relu(u+gather(v)); 0]  (pooledbf region, consumed by G1)
    gatherprep_k<<<dim3(320, BATCH), blk, 0, stream>>>(U, idxp, x_loc, Xc2);

    // 11) G3
    gemm_k<0><<<dim3(128, 4), blk, 0, stream>>>(Wb3, Xc2, bias3, U, nullptr, 320, 0);
    // 12) Xc3 (Xc1 region, consumed by G2)
    gatherprep_k<<<dim3(320, BATCH), blk, 0, stream>>>(U, idxp, x_loc, Xc3);

    // 13) G4
    gemm_k<0><<<dim3(128, 2), blk, 0, stream>>>(Wb4, Xc3, bias4, U, nullptr, 320, 0);
    // 14) fused layer-3 gather + Wloc head
    finalfuse_k<<<dim3(NPTS / 16, BATCH), blk, 0, stream>>>(
        U, idxp, x_loc, Wloc, bloc, out_loc, out_feat);
}

// Round 19
// 272.638 us; speedup vs baseline: 1.0137x; 1.0137x over previous
//
#include <hip/hip_runtime.h>
#include <hip/hip_bf16.h>

#define TPB 256
static constexpr int BATCH = 4;
static constexpr int NPTS  = 4096;
static constexpr int BN    = BATCH * NPTS;   // 16384 columns for all GEMMs

typedef __attribute__((ext_vector_type(8))) short short8v;
typedef __attribute__((ext_vector_type(4))) short short4v;
typedef __attribute__((ext_vector_type(4))) float f32x4;

struct Seg { const float* in; const float* W; int C; int ws; };

__device__ __forceinline__ void gload16(const void* g, void* l) {
    __builtin_amdgcn_global_load_lds(
        (const __attribute__((address_space(1))) void*)g,
        (__attribute__((address_space(3))) void*)l, 16, 0, 0);
}

// ---------------------------------------------------------------------------
// MFMA GEMM (verified): D[m][col] = bias[m] + sum_k A[m][k]*B[k][col]
// ---------------------------------------------------------------------------
template<int EPI>
__global__ __launch_bounds__(256)
void gemm_k(const __hip_bfloat16* __restrict__ A, const __hip_bfloat16* __restrict__ B,
            const float* __restrict__ bias, float* __restrict__ outF,
            __hip_bfloat16* __restrict__ outB, int Kp, int rowOff)
{
    __shared__ short Alds[8192];
    __shared__ short Blds[8704];
    const int tid = threadIdx.x, lane = tid & 63, wid = tid >> 6;
    const int wm = wid & 1, wn = wid >> 1;
    const int n0 = blockIdx.x * 128, m0 = blockIdx.y * 128;

    const char* asrc[4]; short* adst[4];
    #pragma unroll
    for (int t = 0; t < 4; ++t) {
        const int g = (wid * 4 + t) * 64 + lane;
        const int arow = g >> 3, ai = g & 7;
        asrc[t] = (const char*)A +
                  (((size_t)(m0 + arow)) * Kp + ((ai ^ (arow & 7)) << 3)) * 2;
        adst[t] = &Alds[(wid * 4 + t) * 512];
    }
    const char* bsrc[2]; int bkp[2], bc0[2];
    #pragma unroll
    for (int it = 0; it < 2; ++it) {
        const int q = it * 256 + tid;
        bkp[it] = q >> 4;
        bc0[it] = (q & 15) * 8;
        bsrc[it] = (const char*)B +
                   (((size_t)(bkp[it] * 2)) * BN + (n0 + bc0[it])) * 2;
    }

    f32x4 acc[4][4];
    #pragma unroll
    for (int i = 0; i < 4; ++i)
        #pragma unroll
        for (int j = 0; j < 4; ++j) acc[i][j] = (f32x4){0.f, 0.f, 0.f, 0.f};

    const int rl = lane & 15, g4 = lane >> 4;

    const int nkt = Kp >> 6;
    for (int kt = 0; kt < nkt; ++kt) {
        __syncthreads();
        short8v blo[2], bhi[2];
        #pragma unroll
        for (int it = 0; it < 2; ++it) {
            blo[it] = *(const short8v*)(bsrc[it]);
            bhi[it] = *(const short8v*)(bsrc[it] + (size_t)BN * 2);
            bsrc[it] += (size_t)64 * BN * 2;
        }
        #pragma unroll
        for (int t = 0; t < 4; ++t) {
            gload16(asrc[t], adst[t]);
            asrc[t] += 128;
        }
        #pragma unroll
        for (int it = 0; it < 2; ++it) {
            #pragma unroll
            for (int j = 0; j < 8; ++j) {
                const int c = bc0[it] + j;
                const int val = ((int)(unsigned short)blo[it][j]) |
                                (((int)(unsigned short)bhi[it][j]) << 16);
                *(int*)((char*)Blds + c * 136 + bkp[it] * 4) = val;
            }
        }
        __syncthreads();

        #pragma unroll
        for (int ks = 0; ks < 2; ++ks) {
            short8v af[4];
            #pragma unroll
            for (int mf = 0; mf < 4; ++mf) {
                const int row = wm * 64 + mf * 16 + rl;
                const int base = row * 128, sw = (row & 7) << 4;
                const short4v lo = *(const short4v*)((const char*)Alds +
                                    (base + ((ks * 64 + (g4 << 3)) ^ sw)));
                const short4v hi = *(const short4v*)((const char*)Alds +
                                    (base + ((ks * 64 + (g4 << 3) + 32) ^ sw)));
                af[mf] = __builtin_shufflevector(lo, hi, 0,1,2,3,4,5,6,7);
            }
            short8v bfv[4];
            #pragma unroll
            for (int nf = 0; nf < 4; ++nf) {
                const int colr = wn * 64 + nf * 16 + rl;
                const char* bp = (const char*)Blds + colr * 136 + ks * 64 + (g4 << 3);
                const short4v lo = *(const short4v*)bp;
                const short4v hi = *(const short4v*)(bp + 32);
                bfv[nf] = __builtin_shufflevector(lo, hi, 0,1,2,3,4,5,6,7);
            }
            #pragma unroll
            for (int mf = 0; mf < 4; ++mf)
                #pragma unroll
                for (int nf = 0; nf < 4; ++nf)
                    acc[mf][nf] = __builtin_amdgcn_mfma_f32_16x16x32_bf16(
                        af[mf], bfv[nf], acc[mf][nf], 0, 0, 0);
        }
    }

    #pragma unroll
    for (int mf = 0; mf < 4; ++mf) {
        #pragma unroll
        for (int i = 0; i < 4; ++i) {
            const int row = m0 + wm * 64 + mf * 16 + g4 * 4 + i;
            const float bs = bias[row];
            #pragma unroll
            for (int nf = 0; nf < 4; ++nf) {
                const int col = n0 + wn * 64 + nf * 16 + rl;
                float v = acc[mf][nf][i] + bs;
                if (EPI == 1) {
                    v = fmaxf(v, 0.f);
                    outB[(size_t)(rowOff + row) * BN + col] = __float2bfloat16(v);
                } else {
                    outF[(size_t)row * BN + col] = v;
                }
            }
        }
    }
}

// ---------------------------------------------------------------------------
// small f32 conv — h1/h2 only (grid path must stay f32; R13/R17 lesson: bf16
// anywhere in the grid path amplifies x H/2 through bilinear sampling).
// OT=4 -> 1024 blocks = 4 waves/SIMD TLP (latency-bound fix, bit-identical).
// ---------------------------------------------------------------------------
template<bool RELU, int OT>
__global__ __launch_bounds__(TPB)
void conv1x1_k(Seg s0, Seg s1, int nseg, int Ctot,
               const float* __restrict__ bias, float* __restrict__ out, int O)
{
    __shared__ float Wl[131][OT];
    const int n  = blockIdx.x * TPB + threadIdx.x;
    const int o0 = blockIdx.y * OT;
    const int b  = blockIdx.z;
    Seg segs[2] = {s0, s1};
    int off[3]; off[0] = 0;
    #pragma unroll
    for (int k = 0; k < 2; ++k) off[k + 1] = off[k] + (k < nseg ? segs[k].C : 0);
    for (int idx = threadIdx.x; idx < Ctot * OT; idx += TPB) {
        int c = idx / OT, t = idx % OT;
        int k = (nseg > 1 && c >= off[1]) ? 1 : 0;
        Wl[c][t] = segs[k].W[(size_t)(o0 + t) * segs[k].ws + (c - off[k])];
    }
    __syncthreads();
    float acc[OT];
    #pragma unroll
    for (int t = 0; t < OT; ++t) acc[t] = 0.f;
    int cbase = 0;
    for (int k = 0; k < nseg; ++k) {
        const float* ip = segs[k].in + (size_t)b * segs[k].C * NPTS + n;
        const int C = segs[k].C;
        #pragma unroll 8
        for (int cc = 0; cc < C; ++cc) {
            float v = ip[(size_t)cc * NPTS];
            const float4* wr = (const float4*)(&Wl[cbase + cc][0]);
            #pragma unroll
            for (int q = 0; q < OT / 4; ++q) {
                float4 w = wr[q];
                acc[4*q+0] += w.x * v; acc[4*q+1] += w.y * v;
                acc[4*q+2] += w.z * v; acc[4*q+3] += w.w * v;
            }
        }
        cbase += C;
    }
    #pragma unroll
    for (int t = 0; t < OT; ++t) {
        float r = acc[t] + bias[o0 + t];
        if (RELU) r = fmaxf(r, 0.f);
        out[((size_t)b * O + o0 + t) * NPTS + n] = r;
    }
}

// ---------------------------------------------------------------------------
// Fused weight prep: ONE kernel for wcomp + biasfill + all 7 Wb assemblies.
// ---------------------------------------------------------------------------
__global__ __launch_bounds__(TPB)
void prepall_k(const float* __restrict__ Wr1, const float* __restrict__ Wn1,
               const float* __restrict__ Wl1, const float* __restrict__ Wl2,
               const float* __restrict__ bl2, const float* __restrict__ b1,
               const float* __restrict__ Wr2, const float* __restrict__ Wn2,
               const float* __restrict__ Wr3, const float* __restrict__ Wn3,
               const float* __restrict__ b2, const float* __restrict__ b3,
               __hip_bfloat16* __restrict__ Wb1, __hip_bfloat16* __restrict__ Wb2,
               __hip_bfloat16* __restrict__ Wb3, __hip_bfloat16* __restrict__ Wb4,
               float* __restrict__ bu1, float* __restrict__ bv1,
               float* __restrict__ bias3, float* __restrict__ bias4)
{
    __shared__ float wrow[256];
    const int id = blockIdx.x, k = threadIdx.x;

    if (id < 512) {                      // Wb2 + composed Wc + biases
        const int isv = id >> 8, r = id & 255;
        const float* W = isv ? Wn1 : Wr1;
        wrow[k] = W[(size_t)r * 387 + 131 + k];
        __syncthreads();
        float acc = 0.f;
        for (int o = 0; o < 256; ++o) acc += wrow[o] * Wl2[(size_t)o * 256 + k];
        const size_t row = (size_t)(isv * 256 + r);
        Wb2[row * 448 + 131 + k] = __float2bfloat16(acc);
        if (k < 131) Wb2[row * 448 + k] = __float2bfloat16(W[(size_t)r * 387 + k]);
        if (k == 0) {
            float s = 0.f;
            for (int o = 0; o < 256; ++o) s += wrow[o] * bl2[o];
            if (isv) bv1[r] = s; else bu1[r] = b1[r] + s;
        }
    } else if (id < 768) {               // Wb1 (256 rows x 448)
        const int r = id - 512;
        #pragma unroll
        for (int t = 0; t < 2; ++t) {
            const int c = t * 256 + k;
            if (c < 448)
                Wb1[(size_t)r * 448 + c] = __float2bfloat16(Wl1[(size_t)r * 448 + c]);
        }
    } else if (id < 1280) {              // Wb3 (512 rows x 320, src 259 cols)
        const int tb = id - 768, isv = tb >> 8, r = tb & 255;
        const float* W = isv ? Wn2 : Wr2;
        const size_t row = (size_t)(isv * 256 + r);
        #pragma unroll
        for (int t = 0; t < 2; ++t) {
            const int c = t * 256 + k;
            if (c < 320) {
                float v = (c < 259) ? W[(size_t)r * 259 + c] : 0.f;
                Wb3[row * 320 + c] = __float2bfloat16(v);
            }
        }
    } else if (id < 1536) {              // Wb4 (256 rows x 320, src 259 cols)
        const int tb = id - 1280, isv = tb >> 7, r = tb & 127;
        const float* W = isv ? Wn3 : Wr3;
        const size_t row = (size_t)(isv * 128 + r);
        #pragma unroll
        for (int t = 0; t < 2; ++t) {
            const int c = t * 256 + k;
            if (c < 320) {
                float v = (c < 259) ? W[(size_t)r * 259 + c] : 0.f;
                Wb4[row * 320 + c] = __float2bfloat16(v);
            }
        }
    } else {                             // bias fills
        #pragma unroll
        for (int t = 0; t < 3; ++t) {
            const int i = t * 256 + k;
            if (i < 512) bias3[i] = (i < 256) ? b2[i] : 0.f;
            else if (i < 768) { int j = i - 512; bias4[j] = (j < 128) ? b3[j] : 0.f; }
        }
    }
}

// ---------------------------------------------------------------------------
// KNN (K=3). Chunked float4(x,y,z,sq) staging, conflict-free; 16q x 16s.
// Strict < serial scan (exact); butterfly merge keeps full lex compare.
// ---------------------------------------------------------------------------
__global__ __launch_bounds__(TPB)
void knn_k(const float* __restrict__ loc, int* __restrict__ idxp)
{
    __shared__ float4 pt[1024];
    const int b = blockIdx.y;
    const float* L = loc + (size_t)b * 3 * NPTS;

    const int ql = threadIdx.x >> 4;
    const int s  = threadIdx.x & 15;
    const int i  = blockIdx.x * 16 + ql;

    const float xi = L[i], yi = L[NPTS + i], zi = L[2 * NPTS + i];
    float sqi;
    {
        #pragma clang fp contract(off)
        sqi = xi * xi + yi * yi + zi * zi;
    }

    float d0 = 3e38f, d1 = 3e38f, d2 = 3e38f;
    int   i0 = 0x7fffffff, i1 = 0x7fffffff, i2 = 0x7fffffff;

    for (int c = 0; c < NPTS / 1024; ++c) {
        __syncthreads();
        {
            const int base = c * 1024;
            #pragma unroll
            for (int t = 0; t < 4; ++t) {
                const int p = t * 256 + threadIdx.x;
                const float x = L[base + p];
                const float y = L[NPTS + base + p];
                const float z = L[2 * NPTS + base + p];
                float sq;
                {
                    #pragma clang fp contract(off)
                    sq = x * x + y * y + z * z;
                }
                pt[p] = make_float4(x, y, z, sq);
            }
        }
        __syncthreads();

        #pragma unroll 8
        for (int k = 0; k < 1024 / 16; ++k) {
            const int jj = (k << 4) | s;
            const float4 p = pt[jj];
            const int j = (c << 10) | jj;
            float d;
            {
                #pragma clang fp contract(off)
                float dot = xi * p.x + yi * p.y + zi * p.z;
                d = (sqi + p.w) - 2.0f * dot;
            }
            d = (j == i) ? 3e38f : d;
            const bool lt2 = d < d2, lt1 = d < d1, lt0 = d < d0;
            d2 = lt1 ? d1 : (lt2 ? d : d2);  i2 = lt1 ? i1 : (lt2 ? j : i2);
            d1 = lt0 ? d0 : (lt1 ? d : d1);  i1 = lt0 ? i0 : (lt1 ? j : i1);
            d0 = lt0 ? d  : d0;              i0 = lt0 ? j  : i0;
        }
    }

    #pragma unroll
    for (int m = 1; m <= 8; m <<= 1) {
        float e0 = __shfl_xor(d0, m), e1 = __shfl_xor(d1, m), e2 = __shfl_xor(d2, m);
        int   j0 = __shfl_xor(i0, m), j1 = __shfl_xor(i1, m), j2 = __shfl_xor(i2, m);
        float ee[3] = {e0, e1, e2};
        int   jj[3] = {j0, j1, j2};
        #pragma unroll
        for (int t = 0; t < 3; ++t) {
            const float e = ee[t]; const int je = jj[t];
            const bool lt2 = (e < d2 || (e == d2 && je < i2));
            const bool lt1 = (e < d1 || (e == d1 && je < i1));
            const bool lt0 = (e < d0 || (e == d0 && je < i0));
            d2 = lt1 ? d1 : (lt2 ? e : d2);  i2 = lt1 ? i1 : (lt2 ? je : i2);
            d1 = lt0 ? d0 : (lt1 ? e : d1);  i1 = lt0 ? i0 : (lt1 ? je : i1);
            d0 = lt0 ? e  : d0;              i0 = lt0 ? je : i0;
        }
    }

    if (s == 0) {
        idxp[0 * BN + b * NPTS + i] = i0;
        idxp[1 * BN + b * NPTS + i] = i1;
        idxp[2 * BN + b * NPTS + i] = i2;
    }
}

// ---------------------------------------------------------------------------
__global__ __launch_bounds__(TPB)
void gridconv_k(const float* __restrict__ loc, const float* __restrict__ h2,
                const float* __restrict__ Wg, const float* __restrict__ bg,
                float* __restrict__ gridv)
{
    const int n = blockIdx.x * TPB + threadIdx.x;
    const int b = blockIdx.y;
    float a0 = bg[0], a1 = bg[1];
    #pragma unroll
    for (int c = 0; c < 3; ++c) {
        float v = loc[((size_t)b * 3 + c) * NPTS + n];
        a0 += Wg[c] * v; a1 += Wg[67 + c] * v;
    }
    const float* hp = h2 + (size_t)b * 64 * NPTS + n;
    #pragma unroll 4
    for (int c = 0; c < 64; ++c) {
        float v = hp[(size_t)c * NPTS];
        a0 += Wg[3 + c] * v; a1 += Wg[70 + c] * v;
    }
    gridv[((size_t)b * 2 + 0) * NPTS + n] = a0;
    gridv[((size_t)b * 2 + 1) * NPTS + n] = a1;
}

// ---------------------------------------------------------------------------
// grid_sample, 4 channels per thread (verified R16).
// ---------------------------------------------------------------------------
__global__ __launch_bounds__(TPB)
void gridsample4_k(const float* __restrict__ gridv, const float* __restrict__ p0,
                   const float* __restrict__ p1, const float* __restrict__ p2,
                   __hip_bfloat16* __restrict__ pooledbf)
{
    const int n     = blockIdx.x * 64 + (threadIdx.x & 63);
    const int cidx0 = blockIdx.y * 16 + (threadIdx.x >> 6) * 4;
    const int b     = blockIdx.z;
    const float* img; int C, H, cbase;
    if (cidx0 < 64)       { img = p0; C = 64;  H = 112; cbase = 0; }
    else if (cidx0 < 192) { img = p1; C = 128; H = 56;  cbase = 64; }
    else                  { img = p2; C = 256; H = 28;  cbase = 192; }
    const float gx = gridv[((size_t)b * 2 + 0) * NPTS + n];
    const float gy = gridv[((size_t)b * 2 + 1) * NPTS + n];
    float wx, wy; int x0, x1, y0, y1;
    {
        #pragma clang fp contract(off)
        float ix  = ((gx + 1.0f) * (float)H - 1.0f) * 0.5f;
        float iy  = ((gy + 1.0f) * (float)H - 1.0f) * 0.5f;
        float ix0 = floorf(ix), iy0 = floorf(iy);
        wx = ix - ix0; wy = iy - iy0;
        x0 = min(max((int)ix0, 0),     H - 1);
        x1 = min(max((int)ix0 + 1, 0), H - 1);
        y0 = min(max((int)iy0, 0),     H - 1);
        y1 = min(max((int)iy0 + 1, 0), H - 1);
    }
    const float w00 = (1.f - wx) * (1.f - wy), w01 = wx * (1.f - wy);
    const float w10 = (1.f - wx) * wy,         w11 = wx * wy;
    const int plane = H * H;
    const float* base = img + ((size_t)b * C + (cidx0 - cbase)) * plane;
    #pragma unroll
    for (int cc = 0; cc < 4; ++cc) {
        const float* pl = base + (size_t)cc * plane;
        float v = pl[y0*H + x0] * w00 + pl[y0*H + x1] * w01
                + pl[y1*H + x0] * w10 + pl[y1*H + x1] * w11;
        pooledbf[(size_t)(cidx0 + cc) * BN + b * NPTS + n] = __float2bfloat16(v);
    }
}

// ---------------------------------------------------------------------------
// Xc1 prep: rows 0..2 loc-cast, 3..130 feat-cast, 387..447 zero.
// ---------------------------------------------------------------------------
__global__ __launch_bounds__(TPB)
void xc1prep_k(const float* __restrict__ x_loc, const float* __restrict__ x_feat,
               __hip_bfloat16* __restrict__ Xc1)
{
    const int n = blockIdx.x * TPB + threadIdx.x;
    const int y = blockIdx.y, b = blockIdx.z;
    if (y < 3) {
        Xc1[(size_t)y * BN + b * NPTS + n] =
            __float2bfloat16(x_loc[((size_t)b * 3 + y) * NPTS + n]);
    } else if (y < 131) {
        const int c = y - 3;
        Xc1[(size_t)y * BN + b * NPTS + n] =
            __float2bfloat16(x_feat[((size_t)b * 128 + c) * NPTS + n]);
    } else {
        const int row = 387 + (y - 131);
        Xc1[(size_t)row * BN + b * NPTS + n] = __float2bfloat16(0.f);
    }
}

// ---------------------------------------------------------------------------
// Gather + next-layer input prep (verified R16). Grid (320, BATCH).
// ---------------------------------------------------------------------------
__global__ __launch_bounds__(TPB)
void gatherprep_k(const float* __restrict__ uv, const int* __restrict__ idxp,
                  const float* __restrict__ x_loc, __hip_bfloat16* __restrict__ Xc)
{
    __shared__ float vl[NPTS];   // 16 KB
    const int cx = blockIdx.x, b = blockIdx.y;

    if (cx < 3) {
        #pragma unroll
        for (int t = 0; t < NPTS / TPB; ++t) {
            const int n = t * TPB + threadIdx.x;
            Xc[(size_t)cx * BN + b * NPTS + n] =
                __float2bfloat16(x_loc[((size_t)b * 3 + cx) * NPTS + n]);
        }
        return;
    }
    if (cx >= 259) {
        #pragma unroll
        for (int t = 0; t < NPTS / TPB; ++t) {
            const int n = t * TPB + threadIdx.x;
            Xc[(size_t)cx * BN + b * NPTS + n] = __float2bfloat16(0.f);
        }
        return;
    }
    const int c = cx - 3;
    const float* u = uv + (size_t)c * BN + b * NPTS;
    const float* v = uv + (size_t)(256 + c) * BN + b * NPTS;
    #pragma unroll
    for (int t = 0; t < NPTS / TPB; ++t)
        vl[t * TPB + threadIdx.x] = v[t * TPB + threadIdx.x];
    __syncthreads();
    #pragma unroll
    for (int t = 0; t < NPTS / TPB; ++t) {
        const int n = t * TPB + threadIdx.x;
        const int j0 = idxp[0 * BN + b * NPTS + n] & (NPTS - 1);
        const int j1 = idxp[1 * BN + b * NPTS + n] & (NPTS - 1);
        const int j2 = idxp[2 * BN + b * NPTS + n] & (NPTS - 1);
        float r = u[n] + vl[j0] + vl[j1] + vl[j2];
        Xc[(size_t)cx * BN + b * NPTS + n] = __float2bfloat16(fmaxf(r, 0.f));
    }
}

// ---------------------------------------------------------------------------
// layer-3 gather + Wloc head, channel-parallel (verified R14-R16).
// ---------------------------------------------------------------------------
__global__ __launch_bounds__(TPB)
void finalfuse_k(const float* __restrict__ uv, const int* __restrict__ idxp,
                 const float* __restrict__ loc,
                 const float* __restrict__ Wloc, const float* __restrict__ bloc,
                 float* __restrict__ outloc, float* __restrict__ outfeat)
{
    __shared__ float wl[393];
    __shared__ float part[16][16][3];
    for (int idx = threadIdx.x; idx < 393; idx += TPB) wl[idx] = Wloc[idx];
    __syncthreads();

    const int nl = threadIdx.x & 15, cg = threadIdx.x >> 4;
    const int n = blockIdx.x * 16 + nl;
    const int b = blockIdx.y;
    const int j0 = idxp[0 * BN + b * NPTS + n] & (NPTS - 1);
    const int j1 = idxp[1 * BN + b * NPTS + n] & (NPTS - 1);
    const int j2 = idxp[2 * BN + b * NPTS + n] & (NPTS - 1);

    float a0 = 0.f, a1 = 0.f, a2 = 0.f;
    #pragma unroll
    for (int cc = 0; cc < 8; ++cc) {
        const int c = cg * 8 + cc;
        const float* u = uv + (size_t)c * BN + b * NPTS;
        const float* v = uv + (size_t)(128 + c) * BN + b * NPTS;
        float f = fmaxf(u[n] + v[j0] + v[j1] + v[j2], 0.f);
        outfeat[((size_t)b * 128 + c) * NPTS + n] = f;
        a0 += wl[3 + c] * f; a1 += wl[134 + c] * f; a2 += wl[265 + c] * f;
    }
    part[cg][nl][0] = a0; part[cg][nl][1] = a1; part[cg][nl][2] = a2;
    __syncthreads();

    if (cg == 0) {
        float b0 = bloc[0], b1v = bloc[1], b2v = bloc[2];
        float l[3];
        #pragma unroll
        for (int c = 0; c < 3; ++c) {
            float v = loc[((size_t)b * 3 + c) * NPTS + n];
            l[c] = v;
            b0 += wl[c] * v; b1v += wl[131 + c] * v; b2v += wl[262 + c] * v;
        }
        #pragma unroll
        for (int g = 0; g < 16; ++g) {
            b0 += part[g][nl][0]; b1v += part[g][nl][1]; b2v += part[g][nl][2];
        }
        outloc[((size_t)b * 3 + 0) * NPTS + n] = l[0] + tanhf(b0);
        outloc[((size_t)b * 3 + 1) * NPTS + n] = l[1] + tanhf(b1v);
        outloc[((size_t)b * 3 + 2) * NPTS + n] = l[2] + tanhf(b2v);
    }
}

__global__ __launch_bounds__(TPB)
void sentinel_k(float* __restrict__ out, int ntot, float c)
{
    int i = blockIdx.x * TPB + threadIdx.x;
    if (i < ntot) out[i] = c;
}

// ---------------------------------------------------------------------------
extern "C" void kernel_launch(void* const* d_in, const int* in_sizes, int n_in,
                              void* d_out, int out_size, void* d_ws, size_t ws_size,
                              hipStream_t stream)
{
    static const int EXP_INS[26] = {
        49152, 2097152, 3211264, 1605632, 802816,
        8384, 64, 4096, 64, 134, 2,
        114688, 256, 65536, 256,
        99072, 99072, 256, 66304, 66304, 256,
        33152, 33152, 128, 393, 3 };
    constexpr size_t WS_REQ = 16237824ull * 4ull;

    float code = -1.f;
    if (n_in != 26) code = 64.f;
    else {
        bool ok = true;
        for (int i = 0; i < 26; ++i) ok = ok && (in_sizes[i] == EXP_INS[i]);
        if (!ok) code = 24.f;
    }
    if (code < 0.f && out_size != 2146304) code = 32.f;
    if (code < 0.f && ws_size < WS_REQ)    code = 16.f;
    if (code >= 0.f) {
        sentinel_k<<<dim3((out_size + TPB - 1) / TPB), dim3(TPB), 0, stream>>>(
            (float*)d_out, out_size, code);
        return;
    }

    const float* x_loc  = (const float*)d_in[0];
    const float* x_feat = (const float*)d_in[1];
    const float* p0     = (const float*)d_in[2];
    const float* p1     = (const float*)d_in[3];
    const float* p2     = (const float*)d_in[4];
    const float* Ws1 = (const float*)d_in[5];  const float* bs1 = (const float*)d_in[6];
    const float* Ws2 = (const float*)d_in[7];  const float* bs2 = (const float*)d_in[8];
    const float* Wg  = (const float*)d_in[9];  const float* bg  = (const float*)d_in[10];
    const float* Wl1 = (const float*)d_in[11]; const float* bl1 = (const float*)d_in[12];
    const float* Wl2 = (const float*)d_in[13]; const float* bl2 = (const float*)d_in[14];
    const float* Wr1 = (const float*)d_in[15]; const float* Wn1 = (const float*)d_in[16];
    const float* b1  = (const float*)d_in[17];
    const float* Wr2 = (const float*)d_in[18]; const float* Wn2 = (const float*)d_in[19];
    const float* b2  = (const float*)d_in[20];
    const float* Wr3 = (const float*)d_in[21]; const float* Wn3 = (const float*)d_in[22];
    const float* b3  = (const float*)d_in[23];
    const float* Wloc= (const float*)d_in[24]; const float* bloc= (const float*)d_in[25];

    float* ws = (float*)d_ws;
    float* U  = ws;                       // 8,388,608 f: h1/h2 early, uv later
    float* h1 = U;
    float* h2 = U + 1048576;
    __hip_bfloat16* pooledbf = (__hip_bfloat16*)(ws + 8388608);
    __hip_bfloat16* Xc2      = pooledbf;
    __hip_bfloat16* Xc1 = (__hip_bfloat16*)(ws + 12058624);
    __hip_bfloat16* Xc3 = Xc1;
    float* S     = ws + 15728640;
    float* gridv = S;
    int*   idxp  = (int*)(S + 32768);
    float* bu1   = S + 212992;
    float* bv1   = S + 213248;
    float* bias3 = S + 213504;
    float* bias4 = S + 214016;
    __hip_bfloat16* Wb1 = (__hip_bfloat16*)(S + 214272);
    __hip_bfloat16* Wb2 = (__hip_bfloat16*)(S + 271616);
    __hip_bfloat16* Wb3 = (__hip_bfloat16*)(S + 386304);
    __hip_bfloat16* Wb4 = (__hip_bfloat16*)(S + 468224);

    float* out_loc  = (float*)d_out;
    float* out_feat = out_loc + (size_t)BATCH * 3 * NPTS;

    dim3 blk(TPB);
    const int GX = NPTS / TPB;   // 16
    Seg z{nullptr, nullptr, 0, 0};

    // 1) all weight prep in one kernel
    prepall_k<<<dim3(1537), blk, 0, stream>>>(
        Wr1, Wn1, Wl1, Wl2, bl2, b1, Wr2, Wn2, Wr3, Wn3, b2, b3,
        Wb1, Wb2, Wb3, Wb4, bu1, bv1, bias3, bias4);

    // 2-5) front-end (f32 — precision-critical grid path) + knn
    // OT=4 -> 1024 blocks = 2x TLP for the latency-bound convs (bit-identical)
    conv1x1_k<true, 4><<<dim3(GX, 16, BATCH), blk, 0, stream>>>(
        Seg{x_loc, Ws1, 3, 131}, Seg{x_feat, Ws1 + 3, 128, 131}, 2, 131, bs1, h1, 64);
    conv1x1_k<true, 4><<<dim3(GX, 16, BATCH), blk, 0, stream>>>(
        Seg{h1, Ws2, 64, 64}, z, 1, 64, bs2, h2, 64);
    gridconv_k<<<dim3(GX, BATCH), blk, 0, stream>>>(x_loc, h2, Wg, bg, gridv);
    knn_k<<<dim3(NPTS / 16, BATCH), blk, 0, stream>>>(x_loc, idxp);

    // 6) pooled (bf16, 4 channels/thread)
    gridsample4_k<<<dim3(NPTS / 64, 28, BATCH), blk, 0, stream>>>(
        gridv, p0, p1, p2, pooledbf);

    // 7) Xc1 rows 0..130 + zero rows 387..447
    xc1prep_k<<<dim3(GX, 192, BATCH), blk, 0, stream>>>(x_loc, x_feat, Xc1);
    // 8) G1: t = relu(Wl1@pooled + bl1) -> Xc1 rows 131..386
    gemm_k<1><<<dim3(128, 2), blk, 0, stream>>>(Wb1, pooledbf, bl1, nullptr, Xc1, 448, 131);

    // 9) G2: [u1; v1] = Wb2 @ Xc1 + [bu1; bv1]  (overwrites h1/h2 — consumed)
    gemm_k<0><<<dim3(128, 4), blk, 0, stream>>>(Wb2, Xc1, bu1, U, nullptr, 448, 0);
    // 10) Xc2 = [loc; relu(u+gather(v)); 0]  (pooledbf region, consumed by G1)
    gatherprep_k<<<dim3(320, BATCH), blk, 0, stream>>>(U, idxp, x_loc, Xc2);

    // 11) G3
    gemm_k<0><<<dim3(128, 4), blk, 0, stream>>>(Wb3, Xc2, bias3, U, nullptr, 320, 0);
    // 12) Xc3 (Xc1 region, consumed by G2)
    gatherprep_k<<<dim3(320, BATCH), blk, 0, stream>>>(U, idxp, x_loc, Xc3);

    // 13) G4
    gemm_k<0><<<dim3(128, 2), blk, 0, stream>>>(Wb4, Xc3, bias4, U, nullptr, 320, 0);
    // 14) fused layer-3 gather + Wloc head
    finalfuse_k<<<dim3(NPTS / 16, BATCH), blk, 0, stream>>>(
        U, idxp, x_loc, Wloc, bloc, out_loc, out_feat);
}